// Round 14
// baseline (379.039 us; speedup 1.0000x reference)
//
#include <hip/hip_runtime.h>
#include <hip/hip_bf16.h>
#include <cstdint>
#include <cstddef>

typedef __hip_bfloat16 bf16;
using f32x4  = __attribute__((ext_vector_type(4))) float;
using bf16x8 = __attribute__((ext_vector_type(8))) short;

#define DEVI __device__ __forceinline__

DEVI int reg3(int u) { return (u < 49) ? 0 : ((u < 53) ? 1 : 2); }

DEVI unsigned short f2bu(float v) {
  bf16 b = __float2bfloat16(v);
  return *reinterpret_cast<unsigned short*>(&b);
}

// exp-based tanh GELU (max |err| vs exact-erf GELU ~1.5e-3, NaN-free at any x)
DEVI float gelu_f(float v) {
  const float y = 0.7978845608028654f * (v + 0.044715f * v * v * v);
  const float e = __expf(2.0f * y);
  const float th = 1.0f - 2.0f / (e + 1.0f);     // tanh(y)
  return 0.5f * v * (1.0f + th);
}

// async global->LDS, 16B per lane; dest = ldsbase + lane*16 (linear, wave-uniform base)
DEVI void gload_lds16(const void* g, void* l) {
  __builtin_amdgcn_global_load_lds(
      (const __attribute__((address_space(1))) unsigned int*)g,
      (__attribute__((address_space(3))) unsigned int*)l, 16, 0, 0);
}

// ---------- fp32 -> bf16 weight conversion ----------
__global__ __launch_bounds__(256) void cvt_kernel(const float* __restrict__ src,
                                                  bf16* __restrict__ dst, int n)
{
  const int i = blockIdx.x * 256 + threadIdx.x;
  if (i < n) dst[i] = __float2bfloat16(src[i]);
}

// ---------- LayerNorm over C=192 (fp32 in, bf16 out), optional shift+window gather ----------
template<bool PERM>
__global__ __launch_bounds__(256) void ln_kernel(const float* __restrict__ x,
                                                 const float* __restrict__ gw,
                                                 const float* __restrict__ bw,
                                                 bf16* __restrict__ out,
                                                 int grow0)
{
  const int lane = threadIdx.x & 63;
  const int ridx = blockIdx.x * 4 + (threadIdx.x >> 6);
  size_t src;
  if (PERM) {
    const int g   = grow0 + ridx;
    const int wid = g / 49;
    const int nn  = g - wid * 49;
    const int b_  = wid >> 6, wim = wid & 63;
    const int wy  = wim >> 3, wx = wim & 7;
    const int ny  = nn / 7,  nx = nn - (nn / 7) * 7;
    int i = wy * 7 + ny + 3; if (i >= 56) i -= 56;   // shifted coord u reads x[(u+3)%56]
    int j = wx * 7 + nx + 3; if (j >= 56) j -= 56;
    src = (size_t)(b_ * 3136 + i * 56 + j);
  } else {
    src = (size_t)ridx;
  }
  const float* xr = x + src * 192;
  float v0 = xr[lane];
  float v1 = xr[lane + 64];
  float v2 = xr[lane + 128];
  float s = v0 + v1 + v2;
#pragma unroll
  for (int off = 32; off > 0; off >>= 1) s += __shfl_xor(s, off);
  const float mu = s * (1.0f / 192.0f);
  const float d0 = v0 - mu, d1 = v1 - mu, d2 = v2 - mu;
  float vs = d0 * d0 + d1 * d1 + d2 * d2;
#pragma unroll
  for (int off = 32; off > 0; off >>= 1) vs += __shfl_xor(vs, off);
  const float rstd = rsqrtf(vs * (1.0f / 192.0f) + 1e-5f);
  bf16* orow = out + (size_t)ridx * 192;
  orow[lane]       = __float2bfloat16(d0 * rstd * gw[lane]       + bw[lane]);
  orow[lane + 64]  = __float2bfloat16(d1 * rstd * gw[lane + 64]  + bw[lane + 64]);
  orow[lane + 128] = __float2bfloat16(d2 * rstd * gw[lane + 128] + bw[lane + 128]);
}

// ---------- GEMM: out[m,n] = sum_k A[m,k]*Bt[n,k] + bias[n], fused epilogues ----------
// 128x192 tile, BK=64, 2-phase double-buffered, 8 waves (2m x 4n), acc[4][3].
// R14: bf16-output MODEs (0,2) bounce the epilogue through LDS and emit dwordx4
// stores (16B/lane, 1KB/instr) instead of 48 per-lane 2B scalar stores — tests the
// partial-line HBM-write-bound theory (fc1 pinned at ~2.48 TB/s across R8-R13).
// MODE 0: QKV -> bf16 | 1: proj -> fp32 @ un-shifted token + resid | 2: fc1 bf16+GELU | 3: fc2 fp32 +=
template<int MODE>
__global__ __launch_bounds__(512, 4) void gemm_kernel(const bf16* __restrict__ A,
                                                      const bf16* __restrict__ Bt,
                                                      const float* __restrict__ bias,
                                                      const float* __restrict__ resid,
                                                      void* __restrict__ outv,
                                                      int N, int K, int grow0)
{
  __shared__ short lds[2][128 * 64 + 192 * 64];  // 2 x (A[128][64] + B[192][64]) = 80 KiB
  const int tid  = threadIdx.x;
  const int lane = tid & 63;
  const int w    = tid >> 6;           // 0..7
  const int wm   = (w >> 2) * 64;      // 0 | 64
  const int wn   = (w & 3) * 48;       // 0,48,96,144
  const int m0   = blockIdx.y * 128;
  const int n0   = blockIdx.x * 192;
  const int lrow = lane >> 3;
  const int lseg = lane & 7;
  const int ksw  = (lseg * 8) ^ (lrow << 3);   // pre-swizzled source k (elements)

  f32x4 acc[4][3];
#pragma unroll
  for (int i = 0; i < 4; i++)
#pragma unroll
    for (int j = 0; j < 3; j++) acc[i][j] = (f32x4){0.f, 0.f, 0.f, 0.f};

  const int nk = K >> 6;

  auto issue = [&](int buf, int kt) {
    const int k0 = kt << 6;
    short* LA = &lds[buf][0];
    short* LB = &lds[buf][128 * 64];
    // A tile: 16 chunks of 8 rows; wave w covers chunks w*2, w*2+1
#pragma unroll
    for (int i = 0; i < 2; i++) {
      const int chunk = w * 2 + i;
      gload_lds16(A + (size_t)(m0 + chunk * 8 + lrow) * K + (k0 + ksw), LA + chunk * 512);
    }
    // B tile: 24 chunks; wave w covers chunks w*3 .. w*3+2
#pragma unroll
    for (int i = 0; i < 3; i++) {
      const int chunk = w * 3 + i;
      gload_lds16(Bt + (size_t)(n0 + chunk * 8 + lrow) * K + (k0 + ksw), LB + chunk * 512);
    }
  };

  issue(0, 0);
  __syncthreads();

  for (int kt = 0; kt < nk; kt++) {
    const int buf = kt & 1;
    if (kt + 1 < nk) issue(buf ^ 1, kt + 1);   // prefetch next tile into other buffer
    const char* LA = (const char*)&lds[buf][0];
    const char* LB = (const char*)&lds[buf][128 * 64];
#pragma unroll
    for (int kk = 0; kk < 2; kk++) {
      bf16x8 af[4], bg[3];
#pragma unroll
      for (int mf = 0; mf < 4; mf++) {
        const int row = wm + mf * 16 + (lane & 15);
        const int kb  = (kk * 64 + ((lane >> 4) << 4)) ^ ((row & 7) << 4);
        af[mf] = *(const bf16x8*)(LA + row * 128 + kb);
      }
#pragma unroll
      for (int nf = 0; nf < 3; nf++) {
        const int row = wn + nf * 16 + (lane & 15);
        const int kb  = (kk * 64 + ((lane >> 4) << 4)) ^ ((row & 7) << 4);
        bg[nf] = *(const bf16x8*)(LB + row * 128 + kb);
      }
#pragma unroll
      for (int mf = 0; mf < 4; mf++)
#pragma unroll
        for (int nf = 0; nf < 3; nf++)
          acc[mf][nf] = __builtin_amdgcn_mfma_f32_16x16x32_bf16(af[mf], bg[nf], acc[mf][nf], 0, 0, 0);
    }
    __syncthreads();   // drains the prefetch (overlapped with compute) + guards buf reuse
  }

  // epilogue: D layout col=lane&15, row=(lane>>4)*4+r  [m89-verified]
  float bv[3];
  int ncol[3];
#pragma unroll
  for (int nf = 0; nf < 3; nf++) {
    ncol[nf] = n0 + wn + nf * 16 + (lane & 15);
    bv[nf]   = bias[ncol[nf]];
  }

  if constexpr (MODE == 0 || MODE == 2) {
    // --- bf16 output: LDS bounce -> dwordx4 coalesced stores ---
    __syncthreads();                       // all waves done with k-loop LDS
    short* stage = &lds[0][0];             // [128][192] bf16 = 48 KiB (spans both buffers)
#pragma unroll
    for (int mf = 0; mf < 4; mf++)
#pragma unroll
      for (int nf = 0; nf < 3; nf++)
#pragma unroll
        for (int r = 0; r < 4; r++) {
          const int row = wm + mf * 16 + ((lane >> 4) << 2) + r;
          const int col = wn + nf * 16 + (lane & 15);
          float v = acc[mf][nf][r] + bv[nf];
          if constexpr (MODE == 2) v = gelu_f(v);
          stage[row * 192 + col] = (short)f2bu(v);
        }
    __syncthreads();
    bf16* O = (bf16*)outv;
#pragma unroll
    for (int i = 0; i < 6; i++) {
      const int seg = tid + i * 512;       // 0..3071 : 128 rows x 24 16B-segments
      const int row = seg / 24;
      const int cs  = seg - row * 24;
      *(bf16x8*)(O + (size_t)(m0 + row) * N + n0 + cs * 8)
          = *(const bf16x8*)(stage + row * 192 + cs * 8);
    }
  } else {
#pragma unroll
    for (int mf = 0; mf < 4; mf++) {
#pragma unroll
      for (int r = 0; r < 4; r++) {
        const int m = m0 + wm + mf * 16 + ((lane >> 4) << 2) + r;
        if constexpr (MODE == 1) {
          // GLOBAL window row gm (shifted coord u) scatters to token i=(u+3)%56, j=(v+3)%56
          const int gm  = grow0 + m;
          const int wid = gm / 49;
          const int nn  = gm - wid * 49;
          const int b_  = wid >> 6, wim = wid & 63;
          const int wy  = wim >> 3, wx = wim & 7;
          const int ny  = nn / 7, nx = nn - (nn / 7) * 7;
          int i = wy * 7 + ny + 3; if (i >= 56) i -= 56;
          int j = wx * 7 + nx + 3; if (j >= 56) j -= 56;
          const size_t t = (size_t)(b_ * 3136 + i * 56 + j) * 192;
          float* O = (float*)outv;
#pragma unroll
          for (int nf = 0; nf < 3; nf++)
            O[t + ncol[nf]] = acc[mf][nf][r] + bv[nf] + resid[t + ncol[nf]];
        } else {
          float* O = (float*)outv + (size_t)m * N;
#pragma unroll
          for (int nf = 0; nf < 3; nf++)
            O[ncol[nf]] = acc[mf][nf][r] + bv[nf] + O[ncol[nf]];
        }
      }
    }
  }
}

// ---------- MFMA windowed attention (unchanged from R7/R8) ----------
__global__ __launch_bounds__(64) void attn_kernel(const bf16* __restrict__ qkv,
                                                  const float* __restrict__ rpb,
                                                  bf16* __restrict__ aout)
{
  __shared__ unsigned short Vt[32 * 64];
  __shared__ unsigned short Pl[64 * 64];
  __shared__ float Bl[169];
  const int lane = threadIdx.x;
  const int wid  = blockIdx.x;
  const int h    = blockIdx.y;
  const unsigned short* qkvu = (const unsigned short*)qkv;
  const size_t base = (size_t)wid * 49 * 576 + h * 32;

#pragma unroll
  for (int i = 0; i < 3; i++) {
    const int idx = lane + 64 * i;
    if (idx < 169) Bl[idx] = rpb[idx * 6 + h];
  }
#pragma unroll
  for (int i = 0; i < 8; i++)
    ((unsigned long long*)Vt)[lane + 64 * i] = 0ull;

#pragma unroll
  for (int it = 0; it < 7; it++) {
    const int idx = lane + 64 * it;
    if (idx < 392) {
      const int n  = idx >> 3;
      const int d0 = (idx & 7) * 4;
      ushort4 v = *(const ushort4*)(qkvu + base + (size_t)n * 576 + 384 + d0);
      Vt[(d0 + 0) * 64 + (n ^ (((d0 + 0) & 7) << 3))] = v.x;
      Vt[(d0 + 1) * 64 + (n ^ (((d0 + 1) & 7) << 3))] = v.y;
      Vt[(d0 + 2) * 64 + (n ^ (((d0 + 2) & 7) << 3))] = v.z;
      Vt[(d0 + 3) * 64 + (n ^ (((d0 + 3) & 7) << 3))] = v.w;
    }
  }

  bf16x8 qf[4], kf[4];
#pragma unroll
  for (int t = 0; t < 4; t++) {
    int rq = (lane & 15) + t * 16; if (rq > 48) rq = 48;
    qf[t] = *(const bf16x8*)(qkvu + base + (size_t)rq * 576 + ((lane >> 4) * 8));
    kf[t] = *(const bf16x8*)(qkvu + base + (size_t)rq * 576 + 192 + ((lane >> 4) * 8));
  }

  f32x4 s[4][4];
#pragma unroll
  for (int mt = 0; mt < 4; mt++)
#pragma unroll
    for (int nt = 0; nt < 4; nt++)
      s[mt][nt] = __builtin_amdgcn_mfma_f32_16x16x32_bf16(qf[mt], kf[nt],
                    (f32x4){0.f, 0.f, 0.f, 0.f}, 0, 0, 0);

  const int wim = wid & 63;
  const int wy = wim >> 3, wx = wim & 7;
  int labn[4], ch[4], cw[4];
  bool cval[4];
#pragma unroll
  for (int nt = 0; nt < 4; nt++) {
    const int C = (lane & 15) + nt * 16;
    cval[nt] = (C < 49);
    const int cc = cval[nt] ? C : 48;
    ch[nt] = cc / 7; cw[nt] = cc - ch[nt] * 7;
    labn[nt] = reg3(wy * 7 + ch[nt]) * 3 + reg3(wx * 7 + cw[nt]);
  }

#pragma unroll
  for (int mt = 0; mt < 4; mt++) {
    f32x4 rm, sm, inv;
#pragma unroll
    for (int r = 0; r < 4; r++) {
      int R = mt * 16 + ((lane >> 4) << 2) + r; if (R > 48) R = 48;
      const int mh = R / 7, mw = R - (R / 7) * 7;
      const int labm = reg3(wy * 7 + mh) * 3 + reg3(wx * 7 + mw);
#pragma unroll
      for (int nt = 0; nt < 4; nt++) {
        float sv = s[mt][nt][r] * 0.1767766953f
                 + Bl[(mh - ch[nt] + 6) * 13 + (mw - cw[nt] + 6)];
        if (labn[nt] != labm) sv -= 100.f;
        if (!cval[nt]) sv = -3e38f;
        s[mt][nt][r] = sv;
      }
      rm[r] = fmaxf(fmaxf(s[mt][0][r], s[mt][1][r]), fmaxf(s[mt][2][r], s[mt][3][r]));
    }
#pragma unroll
    for (int mk = 1; mk < 16; mk <<= 1)
#pragma unroll
      for (int r = 0; r < 4; r++) rm[r] = fmaxf(rm[r], __shfl_xor(rm[r], mk));
#pragma unroll
    for (int r = 0; r < 4; r++) {
      float acc = 0.f;
#pragma unroll
      for (int nt = 0; nt < 4; nt++) {
        const float p = __expf(s[mt][nt][r] - rm[r]);
        s[mt][nt][r] = p;
        acc += p;
      }
      sm[r] = acc;
    }
#pragma unroll
    for (int mk = 1; mk < 16; mk <<= 1)
#pragma unroll
      for (int r = 0; r < 4; r++) sm[r] += __shfl_xor(sm[r], mk);
#pragma unroll
    for (int r = 0; r < 4; r++) inv[r] = 1.0f / sm[r];
#pragma unroll
    for (int nt = 0; nt < 4; nt++)
#pragma unroll
      for (int r = 0; r < 4; r++) {
        const int R = mt * 16 + ((lane >> 4) << 2) + r;
        const int C = (lane & 15) + nt * 16;
        Pl[R * 64 + (C ^ ((R & 7) << 3))] = f2bu(s[mt][nt][r] * inv[r]);
      }
  }

  f32x4 o[4][2];
#pragma unroll
  for (int mt = 0; mt < 4; mt++)
#pragma unroll
    for (int n2 = 0; n2 < 2; n2++) o[mt][n2] = (f32x4){0.f, 0.f, 0.f, 0.f};
#pragma unroll
  for (int kk = 0; kk < 2; kk++) {
    const int kb = kk * 64 + ((lane >> 4) << 4);
    bf16x8 vb[2];
#pragma unroll
    for (int n2 = 0; n2 < 2; n2++) {
      const int d = (lane & 15) + n2 * 16;
      vb[n2] = *(const bf16x8*)((const char*)Vt + d * 128 + (kb ^ ((d & 7) << 4)));
    }
#pragma unroll
    for (int mt = 0; mt < 4; mt++) {
      const int R = (lane & 15) + mt * 16;
      const bf16x8 pa = *(const bf16x8*)((const char*)Pl + R * 128 + (kb ^ ((R & 7) << 4)));
#pragma unroll
      for (int n2 = 0; n2 < 2; n2++)
        o[mt][n2] = __builtin_amdgcn_mfma_f32_16x16x32_bf16(pa, vb[n2], o[mt][n2], 0, 0, 0);
    }
  }

#pragma unroll
  for (int mt = 0; mt < 4; mt++)
#pragma unroll
    for (int r = 0; r < 4; r++) {
      const int R = mt * 16 + ((lane >> 4) << 2) + r;
      if (R < 49) {
        bf16* orow = aout + (size_t)(wid * 49 + R) * 192 + h * 32;
#pragma unroll
        for (int n2 = 0; n2 < 2; n2++)
          orow[n2 * 16 + (lane & 15)] = __float2bfloat16(o[mt][n2][r]);
      }
    }
}

extern "C" void kernel_launch(void* const* d_in, const int* in_sizes, int n_in,
                              void* d_out, int out_size, void* d_ws, size_t ws_size,
                              hipStream_t stream)
{
  (void)in_sizes; (void)n_in; (void)out_size;
  const float* x     = (const float*)d_in[0];
  const float* ln1g  = (const float*)d_in[1];
  const float* ln1b  = (const float*)d_in[2];
  const float* qkvw  = (const float*)d_in[3];
  const float* qkvb  = (const float*)d_in[4];
  const float* projw = (const float*)d_in[5];
  const float* projb = (const float*)d_in[6];
  const float* rpb   = (const float*)d_in[7];
  const float* ln2g  = (const float*)d_in[8];
  const float* ln2b  = (const float*)d_in[9];
  const float* fc1w  = (const float*)d_in[10];
  const float* fc1b  = (const float*)d_in[11];
  const float* fc2w  = (const float*)d_in[12];
  const float* fc2b  = (const float*)d_in[13];
  float* out = (float*)d_out;
  char* ws   = (char*)d_ws;

  // ---- bf16 weight copies at head of ws (884736 B total) ----
  bf16* wqkv = (bf16*)(ws);              // 110592 el
  bf16* wproj = (bf16*)(ws + 221184);    //  36864 el
  bf16* wfc1 = (bf16*)(ws + 294912);     // 147456 el
  bf16* wfc2 = (bf16*)(ws + 589824);     // 147456 el
  cvt_kernel<<<dim3(432), dim3(256), 0, stream>>>(qkvw, wqkv, 110592);
  cvt_kernel<<<dim3(144), dim3(256), 0, stream>>>(projw, wproj, 36864);
  cvt_kernel<<<dim3(576), dim3(256), 0, stream>>>(fc1w, wfc1, 147456);
  cvt_kernel<<<dim3(576), dim3(256), 0, stream>>>(fc2w, wfc2, 147456);

  char* cws = ws + 884736;
  const size_t avail = (ws_size > 884736ull) ? ws_size - 884736ull : 0;

  // ---- attention pipeline, chunked over batch (permutes are batch-local) ----
  int Bc = 32;
  while (Bc > 2 && (size_t)Bc * 4816896ull > avail) Bc >>= 1;
  const int nb = 32 / Bc;
  bf16* qkv_c  = (bf16*)cws;
  bf16* hwin_c = (bf16*)(cws + (size_t)Bc * 3612672ull);

  for (int c = 0; c < nb; c++) {
    const int R0 = c * Bc * 3136;       // global window-row offset
    const int Mc = Bc * 3136;
    ln_kernel<true><<<dim3(Mc / 4), dim3(256), 0, stream>>>(x, ln1g, ln1b, hwin_c, R0);
    gemm_kernel<0><<<dim3(3, Mc / 128), dim3(512), 0, stream>>>(hwin_c, wqkv, qkvb, nullptr, qkv_c, 576, 192, 0);
    attn_kernel<<<dim3(Bc * 64, 6), dim3(64), 0, stream>>>(qkv_c, rpb, hwin_c);
    gemm_kernel<1><<<dim3(1, Mc / 128), dim3(512), 0, stream>>>(hwin_c, wproj, projb, x, out, 192, 192, R0);
  }

  // ---- MLP (unfused), chunked over rows ----
  int Rc = 100352;
  while (Rc > 6272 && (size_t)Rc * 1920ull > avail) Rc >>= 1;
  bf16* ln2_c = (bf16*)cws;
  bf16* a1_c  = (bf16*)(cws + (size_t)Rc * 384ull);

  for (int r0 = 0; r0 < 100352; r0 += Rc) {
    ln_kernel<false><<<dim3(Rc / 4), dim3(256), 0, stream>>>(out + (size_t)r0 * 192, ln2g, ln2b, ln2_c, 0);
    gemm_kernel<2><<<dim3(4, Rc / 128), dim3(512), 0, stream>>>(ln2_c, wfc1, fc1b, nullptr, a1_c, 768, 192, 0);
    gemm_kernel<3><<<dim3(1, Rc / 128), dim3(512), 0, stream>>>(a1_c, wfc2, fc2b, nullptr, out + (size_t)r0 * 192, 192, 768, 0);
  }
}

// Round 15
// 374.882 us; speedup vs baseline: 1.0111x; 1.0111x over previous
//
#include <hip/hip_runtime.h>
#include <hip/hip_bf16.h>
#include <cstdint>
#include <cstddef>

typedef __hip_bfloat16 bf16;
using f32x4  = __attribute__((ext_vector_type(4))) float;
using bf16x8 = __attribute__((ext_vector_type(8))) short;

#define DEVI __device__ __forceinline__

DEVI int reg3(int u) { return (u < 49) ? 0 : ((u < 53) ? 1 : 2); }

DEVI unsigned short f2bu(float v) {
  bf16 b = __float2bfloat16(v);
  return *reinterpret_cast<unsigned short*>(&b);
}

// exp-based tanh GELU (max |err| vs exact-erf GELU ~1.5e-3, NaN-free at any x)
DEVI float gelu_f(float v) {
  const float y = 0.7978845608028654f * (v + 0.044715f * v * v * v);
  const float e = __expf(2.0f * y);
  const float th = 1.0f - 2.0f / (e + 1.0f);     // tanh(y)
  return 0.5f * v * (1.0f + th);
}

// async global->LDS, 16B per lane; dest = ldsbase + lane*16 (linear, wave-uniform base)
DEVI void gload_lds16(const void* g, void* l) {
  __builtin_amdgcn_global_load_lds(
      (const __attribute__((address_space(1))) unsigned int*)g,
      (__attribute__((address_space(3))) unsigned int*)l, 16, 0, 0);
}

// ---------- fp32 -> bf16 weight conversion ----------
__global__ __launch_bounds__(256) void cvt_kernel(const float* __restrict__ src,
                                                  bf16* __restrict__ dst, int n)
{
  const int i = blockIdx.x * 256 + threadIdx.x;
  if (i < n) dst[i] = __float2bfloat16(src[i]);
}

// ---------- LayerNorm over C=192 (fp32 in, bf16 out), optional shift+window gather ----------
template<bool PERM>
__global__ __launch_bounds__(256) void ln_kernel(const float* __restrict__ x,
                                                 const float* __restrict__ gw,
                                                 const float* __restrict__ bw,
                                                 bf16* __restrict__ out,
                                                 int grow0)
{
  const int lane = threadIdx.x & 63;
  const int ridx = blockIdx.x * 4 + (threadIdx.x >> 6);
  size_t src;
  if (PERM) {
    const int g   = grow0 + ridx;
    const int wid = g / 49;
    const int nn  = g - wid * 49;
    const int b_  = wid >> 6, wim = wid & 63;
    const int wy  = wim >> 3, wx = wim & 7;
    const int ny  = nn / 7,  nx = nn - (nn / 7) * 7;
    int i = wy * 7 + ny + 3; if (i >= 56) i -= 56;   // shifted coord u reads x[(u+3)%56]
    int j = wx * 7 + nx + 3; if (j >= 56) j -= 56;
    src = (size_t)(b_ * 3136 + i * 56 + j);
  } else {
    src = (size_t)ridx;
  }
  const float* xr = x + src * 192;
  float v0 = xr[lane];
  float v1 = xr[lane + 64];
  float v2 = xr[lane + 128];
  float s = v0 + v1 + v2;
#pragma unroll
  for (int off = 32; off > 0; off >>= 1) s += __shfl_xor(s, off);
  const float mu = s * (1.0f / 192.0f);
  const float d0 = v0 - mu, d1 = v1 - mu, d2 = v2 - mu;
  float vs = d0 * d0 + d1 * d1 + d2 * d2;
#pragma unroll
  for (int off = 32; off > 0; off >>= 1) vs += __shfl_xor(vs, off);
  const float rstd = rsqrtf(vs * (1.0f / 192.0f) + 1e-5f);
  bf16* orow = out + (size_t)ridx * 192;
  orow[lane]       = __float2bfloat16(d0 * rstd * gw[lane]       + bw[lane]);
  orow[lane + 64]  = __float2bfloat16(d1 * rstd * gw[lane + 64]  + bw[lane + 64]);
  orow[lane + 128] = __float2bfloat16(d2 * rstd * gw[lane + 128] + bw[lane + 128]);
}

// ---------- persistent-B GEMM, K=192 ----------
// Block loads its 192-col B-panel (72 KB, swizzled) into LDS ONCE, then strides over
// 64-row m-tiles (A dbuf 2x24 KB). Kills per-block B re-staging (was ~45% of VMEM bytes).
// Rows are 384B; swizzle: LDS byte p of row r holds source k-byte p ^ ((r&7)<<4)
// (XOR on bits 4-6 only: bijective per 128B third; bank spread 8x2-way = free).
// 512 thr, 8 waves 2m(32r) x 4n(48c), acc[2][3]. MODE 0: bf16 | 1: proj scatter+resid | 2: bf16+GELU
template<int MODE>
__global__ __launch_bounds__(512) void pgemm_kernel(const bf16* __restrict__ A,
                                                    const bf16* __restrict__ Bt,
                                                    const float* __restrict__ bias,
                                                    const float* __restrict__ resid,
                                                    void* __restrict__ outv,
                                                    int N, int grow0, int MT)
{
  __shared__ short Bp[192 * 192];       // 72 KiB
  __shared__ short La[2][64 * 192];     // 2 x 24 KiB
  const int tid  = threadIdx.x;
  const int lane = tid & 63;
  const int w    = tid >> 6;            // 0..7
  const int wm   = (w >> 2) * 32;       // 0 | 32
  const int wn   = (w & 3) * 48;        // 0,48,96,144
  const int np   = blockIdx.x;          // n-panel (192 cols)
  const int n0   = np * 192;
  const int G    = gridDim.y;
  const int g    = blockIdx.y;
  const int kq   = lane >> 4;           // 0..3 (16B quarter within 64B k-slice)

  // ---- stage B panel once: 72 chunks of 1KB, wave w -> chunks w*9..w*9+8 ----
#pragma unroll
  for (int i = 0; i < 9; i++) {
    const int chunk = w * 9 + i;
    const int idx = chunk * 64 + lane;
    const int row = idx / 24;
    const int seg = idx - row * 24;
    const int ksrc = (seg * 8) ^ ((row & 7) << 3);    // elements
    gload_lds16(Bt + (size_t)(n0 + row) * 192 + ksrc, Bp + chunk * 512);
  }

  auto stageA = [&](int buf, int mt) {
    const int m0 = mt * 64;
#pragma unroll
    for (int i = 0; i < 3; i++) {
      const int chunk = w * 3 + i;
      const int idx = chunk * 64 + lane;
      const int row = idx / 24;
      const int seg = idx - row * 24;
      const int ksrc = (seg * 8) ^ ((row & 7) << 3);
      gload_lds16(A + (size_t)(m0 + row) * 192 + ksrc, &La[buf][0] + chunk * 512);
    }
  };

  int buf = 0;
  stageA(0, g < MT ? g : 0);
  __syncthreads();

  for (int mt = g; mt < MT; mt += G) {
    if (mt + G < MT) stageA(buf ^ 1, mt + G);
    const char* LA = (const char*)&La[buf][0];

    f32x4 acc[2][3];
#pragma unroll
    for (int i = 0; i < 2; i++)
#pragma unroll
      for (int j = 0; j < 3; j++) acc[i][j] = (f32x4){0.f, 0.f, 0.f, 0.f};

#pragma unroll
    for (int kk = 0; kk < 6; kk++) {
      const int q = kk * 64 + (kq << 4);           // k-byte within row (0..383)
      bf16x8 af[2], bg[3];
#pragma unroll
      for (int mf = 0; mf < 2; mf++) {
        const int ar = wm + mf * 16 + (lane & 15);
        af[mf] = *(const bf16x8*)(LA + ar * 384 + (q ^ ((ar & 7) << 4)));
      }
#pragma unroll
      for (int nf = 0; nf < 3; nf++) {
        const int br = wn + nf * 16 + (lane & 15);
        bg[nf] = *(const bf16x8*)((const char*)Bp + br * 384 + (q ^ ((br & 7) << 4)));
      }
#pragma unroll
      for (int mf = 0; mf < 2; mf++)
#pragma unroll
        for (int nf = 0; nf < 3; nf++)
          acc[mf][nf] = __builtin_amdgcn_mfma_f32_16x16x32_bf16(af[mf], bg[nf], acc[mf][nf], 0, 0, 0);
    }

    // epilogue (D layout col=lane&15, row=(lane>>4)*4+r)
    const int m0 = mt * 64;
    float bv[3];
    int ncol[3];
#pragma unroll
    for (int nf = 0; nf < 3; nf++) {
      ncol[nf] = n0 + wn + nf * 16 + (lane & 15);
      bv[nf]   = bias[ncol[nf]];
    }
#pragma unroll
    for (int mf = 0; mf < 2; mf++) {
#pragma unroll
      for (int r = 0; r < 4; r++) {
        const int m = m0 + wm + mf * 16 + ((lane >> 4) << 2) + r;
        if constexpr (MODE == 1) {
          const int gm  = grow0 + m;
          const int wid = gm / 49;
          const int nn  = gm - wid * 49;
          const int b_  = wid >> 6, wim = wid & 63;
          const int wy  = wim >> 3, wx = wim & 7;
          const int ny  = nn / 7, nx = nn - (nn / 7) * 7;
          int i = wy * 7 + ny + 3; if (i >= 56) i -= 56;
          int j = wx * 7 + nx + 3; if (j >= 56) j -= 56;
          const size_t t = (size_t)(b_ * 3136 + i * 56 + j) * 192;
          float* O = (float*)outv;
#pragma unroll
          for (int nf = 0; nf < 3; nf++)
            O[t + ncol[nf]] = acc[mf][nf][r] + bv[nf] + resid[t + ncol[nf]];
        } else {
          bf16* O = (bf16*)outv + (size_t)m * N;
#pragma unroll
          for (int nf = 0; nf < 3; nf++) {
            float v = acc[mf][nf][r] + bv[nf];
            if constexpr (MODE == 2) v = gelu_f(v);
            O[ncol[nf]] = __float2bfloat16(v);
          }
        }
      }
    }
    __syncthreads();   // drain prefetch + guard buf reuse
    buf ^= 1;
  }
}

// ---------- streamed GEMM (fc2 only: K=768, MODE 3 fp32 +=) — R13 structure ----------
template<int MODE>
__global__ __launch_bounds__(512, 4) void gemm_kernel(const bf16* __restrict__ A,
                                                      const bf16* __restrict__ Bt,
                                                      const float* __restrict__ bias,
                                                      const float* __restrict__ resid,
                                                      void* __restrict__ outv,
                                                      int N, int K, int grow0)
{
  __shared__ short lds[2][128 * 64 + 192 * 64];  // 80 KiB
  const int tid  = threadIdx.x;
  const int lane = tid & 63;
  const int w    = tid >> 6;
  const int wm   = (w >> 2) * 64;
  const int wn   = (w & 3) * 48;
  const int m0   = blockIdx.y * 128;
  const int n0   = blockIdx.x * 192;
  const int lrow = lane >> 3;
  const int lseg = lane & 7;
  const int ksw  = (lseg * 8) ^ (lrow << 3);

  f32x4 acc[4][3];
#pragma unroll
  for (int i = 0; i < 4; i++)
#pragma unroll
    for (int j = 0; j < 3; j++) acc[i][j] = (f32x4){0.f, 0.f, 0.f, 0.f};

  const int nk = K >> 6;

  auto issue = [&](int buf, int kt) {
    const int k0 = kt << 6;
    short* LA = &lds[buf][0];
    short* LB = &lds[buf][128 * 64];
#pragma unroll
    for (int i = 0; i < 2; i++) {
      const int chunk = w * 2 + i;
      gload_lds16(A + (size_t)(m0 + chunk * 8 + lrow) * K + (k0 + ksw), LA + chunk * 512);
    }
#pragma unroll
    for (int i = 0; i < 3; i++) {
      const int chunk = w * 3 + i;
      gload_lds16(Bt + (size_t)(n0 + chunk * 8 + lrow) * K + (k0 + ksw), LB + chunk * 512);
    }
  };

  issue(0, 0);
  __syncthreads();

  for (int kt = 0; kt < nk; kt++) {
    const int buf = kt & 1;
    if (kt + 1 < nk) issue(buf ^ 1, kt + 1);
    const char* LA = (const char*)&lds[buf][0];
    const char* LB = (const char*)&lds[buf][128 * 64];
#pragma unroll
    for (int kk = 0; kk < 2; kk++) {
      bf16x8 af[4], bg[3];
#pragma unroll
      for (int mf = 0; mf < 4; mf++) {
        const int row = wm + mf * 16 + (lane & 15);
        const int kb  = (kk * 64 + ((lane >> 4) << 4)) ^ ((row & 7) << 4);
        af[mf] = *(const bf16x8*)(LA + row * 128 + kb);
      }
#pragma unroll
      for (int nf = 0; nf < 3; nf++) {
        const int row = wn + nf * 16 + (lane & 15);
        const int kb  = (kk * 64 + ((lane >> 4) << 4)) ^ ((row & 7) << 4);
        bg[nf] = *(const bf16x8*)(LB + row * 128 + kb);
      }
#pragma unroll
      for (int mf = 0; mf < 4; mf++)
#pragma unroll
        for (int nf = 0; nf < 3; nf++)
          acc[mf][nf] = __builtin_amdgcn_mfma_f32_16x16x32_bf16(af[mf], bg[nf], acc[mf][nf], 0, 0, 0);
    }
    __syncthreads();
  }

  float bv[3];
  int ncol[3];
#pragma unroll
  for (int nf = 0; nf < 3; nf++) {
    ncol[nf] = n0 + wn + nf * 16 + (lane & 15);
    bv[nf]   = bias[ncol[nf]];
  }
#pragma unroll
  for (int mf = 0; mf < 4; mf++) {
#pragma unroll
    for (int r = 0; r < 4; r++) {
      const int m = m0 + wm + mf * 16 + ((lane >> 4) << 2) + r;
      float* O = (float*)outv + (size_t)m * N;
#pragma unroll
      for (int nf = 0; nf < 3; nf++)
        O[ncol[nf]] = acc[mf][nf][r] + bv[nf] + O[ncol[nf]];
    }
  }
}

// ---------- MFMA windowed attention (unchanged from R7/R8) ----------
__global__ __launch_bounds__(64) void attn_kernel(const bf16* __restrict__ qkv,
                                                  const float* __restrict__ rpb,
                                                  bf16* __restrict__ aout)
{
  __shared__ unsigned short Vt[32 * 64];
  __shared__ unsigned short Pl[64 * 64];
  __shared__ float Bl[169];
  const int lane = threadIdx.x;
  const int wid  = blockIdx.x;
  const int h    = blockIdx.y;
  const unsigned short* qkvu = (const unsigned short*)qkv;
  const size_t base = (size_t)wid * 49 * 576 + h * 32;

#pragma unroll
  for (int i = 0; i < 3; i++) {
    const int idx = lane + 64 * i;
    if (idx < 169) Bl[idx] = rpb[idx * 6 + h];
  }
#pragma unroll
  for (int i = 0; i < 8; i++)
    ((unsigned long long*)Vt)[lane + 64 * i] = 0ull;

#pragma unroll
  for (int it = 0; it < 7; it++) {
    const int idx = lane + 64 * it;
    if (idx < 392) {
      const int n  = idx >> 3;
      const int d0 = (idx & 7) * 4;
      ushort4 v = *(const ushort4*)(qkvu + base + (size_t)n * 576 + 384 + d0);
      Vt[(d0 + 0) * 64 + (n ^ (((d0 + 0) & 7) << 3))] = v.x;
      Vt[(d0 + 1) * 64 + (n ^ (((d0 + 1) & 7) << 3))] = v.y;
      Vt[(d0 + 2) * 64 + (n ^ (((d0 + 2) & 7) << 3))] = v.z;
      Vt[(d0 + 3) * 64 + (n ^ (((d0 + 3) & 7) << 3))] = v.w;
    }
  }

  bf16x8 qf[4], kf[4];
#pragma unroll
  for (int t = 0; t < 4; t++) {
    int rq = (lane & 15) + t * 16; if (rq > 48) rq = 48;
    qf[t] = *(const bf16x8*)(qkvu + base + (size_t)rq * 576 + ((lane >> 4) * 8));
    kf[t] = *(const bf16x8*)(qkvu + base + (size_t)rq * 576 + 192 + ((lane >> 4) * 8));
  }

  f32x4 s[4][4];
#pragma unroll
  for (int mt = 0; mt < 4; mt++)
#pragma unroll
    for (int nt = 0; nt < 4; nt++)
      s[mt][nt] = __builtin_amdgcn_mfma_f32_16x16x32_bf16(qf[mt], kf[nt],
                    (f32x4){0.f, 0.f, 0.f, 0.f}, 0, 0, 0);

  const int wim = wid & 63;
  const int wy = wim >> 3, wx = wim & 7;
  int labn[4], ch[4], cw[4];
  bool cval[4];
#pragma unroll
  for (int nt = 0; nt < 4; nt++) {
    const int C = (lane & 15) + nt * 16;
    cval[nt] = (C < 49);
    const int cc = cval[nt] ? C : 48;
    ch[nt] = cc / 7; cw[nt] = cc - ch[nt] * 7;
    labn[nt] = reg3(wy * 7 + ch[nt]) * 3 + reg3(wx * 7 + cw[nt]);
  }

#pragma unroll
  for (int mt = 0; mt < 4; mt++) {
    f32x4 rm, sm, inv;
#pragma unroll
    for (int r = 0; r < 4; r++) {
      int R = mt * 16 + ((lane >> 4) << 2) + r; if (R > 48) R = 48;
      const int mh = R / 7, mw = R - (R / 7) * 7;
      const int labm = reg3(wy * 7 + mh) * 3 + reg3(wx * 7 + mw);
#pragma unroll
      for (int nt = 0; nt < 4; nt++) {
        float sv = s[mt][nt][r] * 0.1767766953f
                 + Bl[(mh - ch[nt] + 6) * 13 + (mw - cw[nt] + 6)];
        if (labn[nt] != labm) sv -= 100.f;
        if (!cval[nt]) sv = -3e38f;
        s[mt][nt][r] = sv;
      }
      rm[r] = fmaxf(fmaxf(s[mt][0][r], s[mt][1][r]), fmaxf(s[mt][2][r], s[mt][3][r]));
    }
#pragma unroll
    for (int mk = 1; mk < 16; mk <<= 1)
#pragma unroll
      for (int r = 0; r < 4; r++) rm[r] = fmaxf(rm[r], __shfl_xor(rm[r], mk));
#pragma unroll
    for (int r = 0; r < 4; r++) {
      float acc = 0.f;
#pragma unroll
      for (int nt = 0; nt < 4; nt++) {
        const float p = __expf(s[mt][nt][r] - rm[r]);
        s[mt][nt][r] = p;
        acc += p;
      }
      sm[r] = acc;
    }
#pragma unroll
    for (int mk = 1; mk < 16; mk <<= 1)
#pragma unroll
      for (int r = 0; r < 4; r++) sm[r] += __shfl_xor(sm[r], mk);
#pragma unroll
    for (int r = 0; r < 4; r++) inv[r] = 1.0f / sm[r];
#pragma unroll
    for (int nt = 0; nt < 4; nt++)
#pragma unroll
      for (int r = 0; r < 4; r++) {
        const int R = mt * 16 + ((lane >> 4) << 2) + r;
        const int C = (lane & 15) + nt * 16;
        Pl[R * 64 + (C ^ ((R & 7) << 3))] = f2bu(s[mt][nt][r] * inv[r]);
      }
  }

  f32x4 o[4][2];
#pragma unroll
  for (int mt = 0; mt < 4; mt++)
#pragma unroll
    for (int n2 = 0; n2 < 2; n2++) o[mt][n2] = (f32x4){0.f, 0.f, 0.f, 0.f};
#pragma unroll
  for (int kk = 0; kk < 2; kk++) {
    const int kb = kk * 64 + ((lane >> 4) << 4);
    bf16x8 vb[2];
#pragma unroll
    for (int n2 = 0; n2 < 2; n2++) {
      const int d = (lane & 15) + n2 * 16;
      vb[n2] = *(const bf16x8*)((const char*)Vt + d * 128 + (kb ^ ((d & 7) << 4)));
    }
#pragma unroll
    for (int mt = 0; mt < 4; mt++) {
      const int R = (lane & 15) + mt * 16;
      const bf16x8 pa = *(const bf16x8*)((const char*)Pl + R * 128 + (kb ^ ((R & 7) << 4)));
#pragma unroll
      for (int n2 = 0; n2 < 2; n2++)
        o[mt][n2] = __builtin_amdgcn_mfma_f32_16x16x32_bf16(pa, vb[n2], o[mt][n2], 0, 0, 0);
    }
  }

#pragma unroll
  for (int mt = 0; mt < 4; mt++)
#pragma unroll
    for (int r = 0; r < 4; r++) {
      const int R = mt * 16 + ((lane >> 4) << 2) + r;
      if (R < 49) {
        bf16* orow = aout + (size_t)(wid * 49 + R) * 192 + h * 32;
#pragma unroll
        for (int n2 = 0; n2 < 2; n2++)
          orow[n2 * 16 + (lane & 15)] = __float2bfloat16(o[mt][n2][r]);
      }
    }
}

extern "C" void kernel_launch(void* const* d_in, const int* in_sizes, int n_in,
                              void* d_out, int out_size, void* d_ws, size_t ws_size,
                              hipStream_t stream)
{
  (void)in_sizes; (void)n_in; (void)out_size;
  const float* x     = (const float*)d_in[0];
  const float* ln1g  = (const float*)d_in[1];
  const float* ln1b  = (const float*)d_in[2];
  const float* qkvw  = (const float*)d_in[3];
  const float* qkvb  = (const float*)d_in[4];
  const float* projw = (const float*)d_in[5];
  const float* projb = (const float*)d_in[6];
  const float* rpb   = (const float*)d_in[7];
  const float* ln2g  = (const float*)d_in[8];
  const float* ln2b  = (const float*)d_in[9];
  const float* fc1w  = (const float*)d_in[10];
  const float* fc1b  = (const float*)d_in[11];
  const float* fc2w  = (const float*)d_in[12];
  const float* fc2b  = (const float*)d_in[13];
  float* out = (float*)d_out;
  char* ws   = (char*)d_ws;

  // ---- bf16 weight copies at head of ws (884736 B total) ----
  bf16* wqkv = (bf16*)(ws);              // 110592 el
  bf16* wproj = (bf16*)(ws + 221184);    //  36864 el
  bf16* wfc1 = (bf16*)(ws + 294912);     // 147456 el
  bf16* wfc2 = (bf16*)(ws + 589824);     // 147456 el
  cvt_kernel<<<dim3(432), dim3(256), 0, stream>>>(qkvw, wqkv, 110592);
  cvt_kernel<<<dim3(144), dim3(256), 0, stream>>>(projw, wproj, 36864);
  cvt_kernel<<<dim3(576), dim3(256), 0, stream>>>(fc1w, wfc1, 147456);
  cvt_kernel<<<dim3(576), dim3(256), 0, stream>>>(fc2w, wfc2, 147456);

  char* cws = ws + 884736;
  const size_t avail = (ws_size > 884736ull) ? ws_size - 884736ull : 0;

  // ---- attention pipeline, chunked over batch (permutes are batch-local) ----
  int Bc = 32;
  while (Bc > 2 && (size_t)Bc * 4816896ull > avail) Bc >>= 1;
  const int nb = 32 / Bc;
  bf16* qkv_c  = (bf16*)cws;
  bf16* hwin_c = (bf16*)(cws + (size_t)Bc * 3612672ull);

  for (int c = 0; c < nb; c++) {
    const int R0 = c * Bc * 3136;       // global window-row offset
    const int Mc = Bc * 3136;
    const int MT = Mc / 64;             // 64-row m-tiles
    ln_kernel<true><<<dim3(Mc / 4), dim3(256), 0, stream>>>(x, ln1g, ln1b, hwin_c, R0);
    pgemm_kernel<0><<<dim3(3, 170), dim3(512), 0, stream>>>(hwin_c, wqkv, qkvb, nullptr, qkv_c, 576, 0, MT);
    attn_kernel<<<dim3(Bc * 64, 6), dim3(64), 0, stream>>>(qkv_c, rpb, hwin_c);
    pgemm_kernel<1><<<dim3(1, 256), dim3(512), 0, stream>>>(hwin_c, wproj, projb, x, out, 192, R0, MT);
  }

  // ---- MLP (unfused), chunked over rows ----
  int Rc = 100352;
  while (Rc > 6272 && (size_t)Rc * 1920ull > avail) Rc >>= 1;
  bf16* ln2_c = (bf16*)cws;
  bf16* a1_c  = (bf16*)(cws + (size_t)Rc * 384ull);

  for (int r0 = 0; r0 < 100352; r0 += Rc) {
    ln_kernel<false><<<dim3(Rc / 4), dim3(256), 0, stream>>>(out + (size_t)r0 * 192, ln2g, ln2b, ln2_c, 0);
    pgemm_kernel<2><<<dim3(4, 128), dim3(512), 0, stream>>>(ln2_c, wfc1, fc1b, nullptr, a1_c, 768, 0, Rc / 64);
    gemm_kernel<3><<<dim3(1, Rc / 128), dim3(512), 0, stream>>>(a1_c, wfc2, fc2b, nullptr, out + (size_t)r0 * 192, 192, 768, 0);
  }
}

// Round 16
// 359.842 us; speedup vs baseline: 1.0533x; 1.0418x over previous
//
#include <hip/hip_runtime.h>
#include <hip/hip_bf16.h>
#include <cstdint>
#include <cstddef>

typedef __hip_bfloat16 bf16;
using f32x4  = __attribute__((ext_vector_type(4))) float;
using bf16x8 = __attribute__((ext_vector_type(8))) short;

#define DEVI __device__ __forceinline__
// counted VMEM wait: N ops may remain outstanding (T4). "memory" clobber pins ordering.
#define WAITVM(N) asm volatile("s_waitcnt vmcnt(" #N ")" ::: "memory")

DEVI int reg3(int u) { return (u < 49) ? 0 : ((u < 53) ? 1 : 2); }

DEVI unsigned short f2bu(float v) {
  bf16 b = __float2bfloat16(v);
  return *reinterpret_cast<unsigned short*>(&b);
}

// exp-based tanh GELU (max |err| vs exact-erf GELU ~1.5e-3, NaN-free at any x)
DEVI float gelu_f(float v) {
  const float y = 0.7978845608028654f * (v + 0.044715f * v * v * v);
  const float e = __expf(2.0f * y);
  const float th = 1.0f - 2.0f / (e + 1.0f);     // tanh(y)
  return 0.5f * v * (1.0f + th);
}

// async global->LDS, 16B per lane; dest = ldsbase + lane*16 (linear, wave-uniform base)
DEVI void gload_lds16(const void* g, void* l) {
  __builtin_amdgcn_global_load_lds(
      (const __attribute__((address_space(1))) unsigned int*)g,
      (__attribute__((address_space(3))) unsigned int*)l, 16, 0, 0);
}

// ---------- fp32 -> bf16 weight conversion ----------
__global__ __launch_bounds__(256) void cvt_kernel(const float* __restrict__ src,
                                                  bf16* __restrict__ dst, int n)
{
  const int i = blockIdx.x * 256 + threadIdx.x;
  if (i < n) dst[i] = __float2bfloat16(src[i]);
}

// ---------- LayerNorm over C=192 (fp32 in, bf16 out), optional shift+window gather ----------
template<bool PERM>
__global__ __launch_bounds__(256) void ln_kernel(const float* __restrict__ x,
                                                 const float* __restrict__ gw,
                                                 const float* __restrict__ bw,
                                                 bf16* __restrict__ out,
                                                 int grow0)
{
  const int lane = threadIdx.x & 63;
  const int ridx = blockIdx.x * 4 + (threadIdx.x >> 6);
  size_t src;
  if (PERM) {
    const int g   = grow0 + ridx;
    const int wid = g / 49;
    const int nn  = g - wid * 49;
    const int b_  = wid >> 6, wim = wid & 63;
    const int wy  = wim >> 3, wx = wim & 7;
    const int ny  = nn / 7,  nx = nn - (nn / 7) * 7;
    int i = wy * 7 + ny + 3; if (i >= 56) i -= 56;   // shifted coord u reads x[(u+3)%56]
    int j = wx * 7 + nx + 3; if (j >= 56) j -= 56;
    src = (size_t)(b_ * 3136 + i * 56 + j);
  } else {
    src = (size_t)ridx;
  }
  const float* xr = x + src * 192;
  float v0 = xr[lane];
  float v1 = xr[lane + 64];
  float v2 = xr[lane + 128];
  float s = v0 + v1 + v2;
#pragma unroll
  for (int off = 32; off > 0; off >>= 1) s += __shfl_xor(s, off);
  const float mu = s * (1.0f / 192.0f);
  const float d0 = v0 - mu, d1 = v1 - mu, d2 = v2 - mu;
  float vs = d0 * d0 + d1 * d1 + d2 * d2;
#pragma unroll
  for (int off = 32; off > 0; off >>= 1) vs += __shfl_xor(vs, off);
  const float rstd = rsqrtf(vs * (1.0f / 192.0f) + 1e-5f);
  bf16* orow = out + (size_t)ridx * 192;
  orow[lane]       = __float2bfloat16(d0 * rstd * gw[lane]       + bw[lane]);
  orow[lane + 64]  = __float2bfloat16(d1 * rstd * gw[lane + 64]  + bw[lane + 64]);
  orow[lane + 128] = __float2bfloat16(d2 * rstd * gw[lane + 128] + bw[lane + 128]);
}

// ---------- persistent-B GEMM, K=192, counted-vmcnt pipeline (T3/T4) ----------
// Raw s_barrier, vmcnt NEVER drained to 0 in the loop: stores retire in background,
// next tile's loads are 1 tile ahead. Per-wave per-tile VMEM issue order:
//   [3 stage loads (t+1)] then [S epilogue stores (t)]  (MODE 1: +24 resid loads -> S=48)
// At iter-t top: outstanding = loads(t)(3, oldest) + S  ->  vmcnt(S) retires loads(t).
// Buffer safety: La[buf^1] overwritten only after the barrier that proves all waves
// finished computing tile t-1 from it.  B-panel (72 KB) staged once.
template<int MODE>
__global__ __launch_bounds__(512) void pgemm_kernel(const bf16* __restrict__ A,
                                                    const bf16* __restrict__ Bt,
                                                    const float* __restrict__ bias,
                                                    const float* __restrict__ resid,
                                                    void* __restrict__ outv,
                                                    int N, int grow0, int MT)
{
  __shared__ short Bp[192 * 192];       // 72 KiB
  __shared__ short La[2][64 * 192];     // 2 x 24 KiB
  const int tid  = threadIdx.x;
  const int lane = tid & 63;
  const int w    = tid >> 6;            // 0..7
  const int wm   = (w >> 2) * 32;       // 0 | 32
  const int wn   = (w & 3) * 48;        // 0,48,96,144
  const int n0   = blockIdx.x * 192;
  const int G    = gridDim.y;
  const int g    = blockIdx.y;
  const int kq   = lane >> 4;           // 0..3

  // ---- bias hoist (pre-prologue; drained by the prologue __syncthreads) ----
  float bv[3];
  int ncol[3];
#pragma unroll
  for (int nf = 0; nf < 3; nf++) {
    ncol[nf] = n0 + wn + nf * 16 + (lane & 15);
    bv[nf]   = bias[ncol[nf]];
  }

  // ---- stage B panel once: 72 chunks of 1KB ----
#pragma unroll
  for (int i = 0; i < 9; i++) {
    const int chunk = w * 9 + i;
    const int idx = chunk * 64 + lane;
    const int row = idx / 24;
    const int seg = idx - row * 24;
    const int ksrc = (seg * 8) ^ ((row & 7) << 3);    // elements
    gload_lds16(Bt + (size_t)(n0 + row) * 192 + ksrc, Bp + chunk * 512);
  }

  auto stageA = [&](int buf, int mt) {
    const int m0 = mt * 64;
#pragma unroll
    for (int i = 0; i < 3; i++) {
      const int chunk = w * 3 + i;
      const int idx = chunk * 64 + lane;
      const int row = idx / 24;
      const int seg = idx - row * 24;
      const int ksrc = (seg * 8) ^ ((row & 7) << 3);
      gload_lds16(A + (size_t)(m0 + row) * 192 + ksrc, &La[buf][0] + chunk * 512);
    }
  };

  int buf = 0;
  if (g < MT) stageA(0, g);
  __syncthreads();                      // one-time full drain (B, A0, bias)

  for (int mt = g; mt < MT; mt += G) {
    if constexpr (MODE == 1) { WAITVM(48); } else { WAITVM(24); }
    __builtin_amdgcn_s_barrier();       // raw barrier: NO vmcnt(0) drain

    const char* LA = (const char*)&La[buf][0];
    f32x4 acc[2][3];
#pragma unroll
    for (int i = 0; i < 2; i++)
#pragma unroll
      for (int j = 0; j < 3; j++) acc[i][j] = (f32x4){0.f, 0.f, 0.f, 0.f};

#pragma unroll
    for (int kk = 0; kk < 6; kk++) {
      const int q = kk * 64 + (kq << 4);
      bf16x8 af[2], bg[3];
#pragma unroll
      for (int mf = 0; mf < 2; mf++) {
        const int ar = wm + mf * 16 + (lane & 15);
        af[mf] = *(const bf16x8*)(LA + ar * 384 + (q ^ ((ar & 7) << 4)));
      }
#pragma unroll
      for (int nf = 0; nf < 3; nf++) {
        const int br = wn + nf * 16 + (lane & 15);
        bg[nf] = *(const bf16x8*)((const char*)Bp + br * 384 + (q ^ ((br & 7) << 4)));
      }
#pragma unroll
      for (int mf = 0; mf < 2; mf++)
#pragma unroll
        for (int nf = 0; nf < 3; nf++)
          acc[mf][nf] = __builtin_amdgcn_mfma_f32_16x16x32_bf16(af[mf], bg[nf], acc[mf][nf], 0, 0, 0);
    }

    // prefetch next tile (issued BEFORE this tile's stores: keeps count order loads<stores)
    if (mt + G < MT) stageA(buf ^ 1, mt + G);

    // epilogue (D layout col=lane&15, row=(lane>>4)*4+r): exactly 24 stores/wave
    const int m0 = mt * 64;
#pragma unroll
    for (int mf = 0; mf < 2; mf++) {
#pragma unroll
      for (int r = 0; r < 4; r++) {
        const int m = m0 + wm + mf * 16 + ((lane >> 4) << 2) + r;
        if constexpr (MODE == 1) {
          const int gm  = grow0 + m;
          const int wid = gm / 49;
          const int nn  = gm - wid * 49;
          const int b_  = wid >> 6, wim = wid & 63;
          const int wy  = wim >> 3, wx = wim & 7;
          const int ny  = nn / 7, nx = nn - (nn / 7) * 7;
          int i = wy * 7 + ny + 3; if (i >= 56) i -= 56;
          int j = wx * 7 + nx + 3; if (j >= 56) j -= 56;
          const size_t t = (size_t)(b_ * 3136 + i * 56 + j) * 192;
          float* O = (float*)outv;
#pragma unroll
          for (int nf = 0; nf < 3; nf++)
            O[t + ncol[nf]] = acc[mf][nf][r] + bv[nf] + resid[t + ncol[nf]];
        } else {
          bf16* O = (bf16*)outv + (size_t)m * N;
#pragma unroll
          for (int nf = 0; nf < 3; nf++) {
            float v = acc[mf][nf][r] + bv[nf];
            if constexpr (MODE == 2) v = gelu_f(v);
            O[ncol[nf]] = __float2bfloat16(v);
          }
        }
      }
    }
    buf ^= 1;
  }
}

// ---------- streamed GEMM (fc2: K=768, MODE 3 fp32 +=), counted-vmcnt 2-phase ----------
__global__ __launch_bounds__(512, 4) void gemm_kernel(const bf16* __restrict__ A,
                                                      const bf16* __restrict__ Bt,
                                                      const float* __restrict__ bias,
                                                      void* __restrict__ outv,
                                                      int N, int K)
{
  __shared__ short lds[2][128 * 64 + 192 * 64];  // 80 KiB
  const int tid  = threadIdx.x;
  const int lane = tid & 63;
  const int w    = tid >> 6;
  const int wm   = (w >> 2) * 64;
  const int wn   = (w & 3) * 48;
  const int m0   = blockIdx.y * 128;
  const int n0   = blockIdx.x * 192;
  const int lrow = lane >> 3;
  const int lseg = lane & 7;
  const int ksw  = (lseg * 8) ^ (lrow << 3);

  f32x4 acc[4][3];
#pragma unroll
  for (int i = 0; i < 4; i++)
#pragma unroll
    for (int j = 0; j < 3; j++) acc[i][j] = (f32x4){0.f, 0.f, 0.f, 0.f};

  const int nk = K >> 6;

  auto issue = [&](int buf, int kt) {
    const int k0 = kt << 6;
    short* LA = &lds[buf][0];
    short* LB = &lds[buf][128 * 64];
#pragma unroll
    for (int i = 0; i < 2; i++) {
      const int chunk = w * 2 + i;
      gload_lds16(A + (size_t)(m0 + chunk * 8 + lrow) * K + (k0 + ksw), LA + chunk * 512);
    }
#pragma unroll
    for (int i = 0; i < 3; i++) {
      const int chunk = w * 3 + i;
      gload_lds16(Bt + (size_t)(n0 + chunk * 8 + lrow) * K + (k0 + ksw), LB + chunk * 512);
    }
  };

  issue(0, 0);
  __syncthreads();                      // one-time drain of k-tile 0
  int buf = 0;

  for (int kt = 0; kt < nk; kt++) {
    if (kt + 1 < nk) {
      issue(buf ^ 1, kt + 1);           // 5 loads ahead in flight
      WAITVM(5);                        // retire loads(kt) (oldest 5 of 10)
    } else {
      WAITVM(0);                        // last tile: must be fully landed
    }
    __builtin_amdgcn_s_barrier();
    const char* LA = (const char*)&lds[buf][0];
    const char* LB = (const char*)&lds[buf][128 * 64];
#pragma unroll
    for (int kk = 0; kk < 2; kk++) {
      bf16x8 af[4], bg[3];
#pragma unroll
      for (int mf = 0; mf < 4; mf++) {
        const int row = wm + mf * 16 + (lane & 15);
        const int kb  = (kk * 64 + ((lane >> 4) << 4)) ^ ((row & 7) << 4);
        af[mf] = *(const bf16x8*)(LA + row * 128 + kb);
      }
#pragma unroll
      for (int nf = 0; nf < 3; nf++) {
        const int row = wn + nf * 16 + (lane & 15);
        const int kb  = (kk * 64 + ((lane >> 4) << 4)) ^ ((row & 7) << 4);
        bg[nf] = *(const bf16x8*)(LB + row * 128 + kb);
      }
#pragma unroll
      for (int mf = 0; mf < 4; mf++)
#pragma unroll
        for (int nf = 0; nf < 3; nf++)
          acc[mf][nf] = __builtin_amdgcn_mfma_f32_16x16x32_bf16(af[mf], bg[nf], acc[mf][nf], 0, 0, 0);
    }
    __builtin_amdgcn_s_barrier();       // guard buf reuse (no drain needed: next iter's
    buf ^= 1;                           // vmcnt only gates NEW loads, issued after this)
  }

  float bv[3];
  int ncol[3];
#pragma unroll
  for (int nf = 0; nf < 3; nf++) {
    ncol[nf] = n0 + wn + nf * 16 + (lane & 15);
    bv[nf]   = bias[ncol[nf]];
  }
#pragma unroll
  for (int mf = 0; mf < 4; mf++) {
#pragma unroll
    for (int r = 0; r < 4; r++) {
      const int m = m0 + wm + mf * 16 + ((lane >> 4) << 2) + r;
      float* O = (float*)outv + (size_t)m * N;
#pragma unroll
      for (int nf = 0; nf < 3; nf++)
        O[ncol[nf]] = acc[mf][nf][r] + bv[nf] + O[ncol[nf]];
    }
  }
}

// ---------- MFMA windowed attention (unchanged from R7/R8) ----------
__global__ __launch_bounds__(64) void attn_kernel(const bf16* __restrict__ qkv,
                                                  const float* __restrict__ rpb,
                                                  bf16* __restrict__ aout)
{
  __shared__ unsigned short Vt[32 * 64];
  __shared__ unsigned short Pl[64 * 64];
  __shared__ float Bl[169];
  const int lane = threadIdx.x;
  const int wid  = blockIdx.x;
  const int h    = blockIdx.y;
  const unsigned short* qkvu = (const unsigned short*)qkv;
  const size_t base = (size_t)wid * 49 * 576 + h * 32;

#pragma unroll
  for (int i = 0; i < 3; i++) {
    const int idx = lane + 64 * i;
    if (idx < 169) Bl[idx] = rpb[idx * 6 + h];
  }
#pragma unroll
  for (int i = 0; i < 8; i++)
    ((unsigned long long*)Vt)[lane + 64 * i] = 0ull;

#pragma unroll
  for (int it = 0; it < 7; it++) {
    const int idx = lane + 64 * it;
    if (idx < 392) {
      const int n  = idx >> 3;
      const int d0 = (idx & 7) * 4;
      ushort4 v = *(const ushort4*)(qkvu + base + (size_t)n * 576 + 384 + d0);
      Vt[(d0 + 0) * 64 + (n ^ (((d0 + 0) & 7) << 3))] = v.x;
      Vt[(d0 + 1) * 64 + (n ^ (((d0 + 1) & 7) << 3))] = v.y;
      Vt[(d0 + 2) * 64 + (n ^ (((d0 + 2) & 7) << 3))] = v.z;
      Vt[(d0 + 3) * 64 + (n ^ (((d0 + 3) & 7) << 3))] = v.w;
    }
  }

  bf16x8 qf[4], kf[4];
#pragma unroll
  for (int t = 0; t < 4; t++) {
    int rq = (lane & 15) + t * 16; if (rq > 48) rq = 48;
    qf[t] = *(const bf16x8*)(qkvu + base + (size_t)rq * 576 + ((lane >> 4) * 8));
    kf[t] = *(const bf16x8*)(qkvu + base + (size_t)rq * 576 + 192 + ((lane >> 4) * 8));
  }

  f32x4 s[4][4];
#pragma unroll
  for (int mt = 0; mt < 4; mt++)
#pragma unroll
    for (int nt = 0; nt < 4; nt++)
      s[mt][nt] = __builtin_amdgcn_mfma_f32_16x16x32_bf16(qf[mt], kf[nt],
                    (f32x4){0.f, 0.f, 0.f, 0.f}, 0, 0, 0);

  const int wim = wid & 63;
  const int wy = wim >> 3, wx = wim & 7;
  int labn[4], ch[4], cw[4];
  bool cval[4];
#pragma unroll
  for (int nt = 0; nt < 4; nt++) {
    const int C = (lane & 15) + nt * 16;
    cval[nt] = (C < 49);
    const int cc = cval[nt] ? C : 48;
    ch[nt] = cc / 7; cw[nt] = cc - ch[nt] * 7;
    labn[nt] = reg3(wy * 7 + ch[nt]) * 3 + reg3(wx * 7 + cw[nt]);
  }

#pragma unroll
  for (int mt = 0; mt < 4; mt++) {
    f32x4 rm, sm, inv;
#pragma unroll
    for (int r = 0; r < 4; r++) {
      int R = mt * 16 + ((lane >> 4) << 2) + r; if (R > 48) R = 48;
      const int mh = R / 7, mw = R - (R / 7) * 7;
      const int labm = reg3(wy * 7 + mh) * 3 + reg3(wx * 7 + mw);
#pragma unroll
      for (int nt = 0; nt < 4; nt++) {
        float sv = s[mt][nt][r] * 0.1767766953f
                 + Bl[(mh - ch[nt] + 6) * 13 + (mw - cw[nt] + 6)];
        if (labn[nt] != labm) sv -= 100.f;
        if (!cval[nt]) sv = -3e38f;
        s[mt][nt][r] = sv;
      }
      rm[r] = fmaxf(fmaxf(s[mt][0][r], s[mt][1][r]), fmaxf(s[mt][2][r], s[mt][3][r]));
    }
#pragma unroll
    for (int mk = 1; mk < 16; mk <<= 1)
#pragma unroll
      for (int r = 0; r < 4; r++) rm[r] = fmaxf(rm[r], __shfl_xor(rm[r], mk));
#pragma unroll
    for (int r = 0; r < 4; r++) {
      float acc = 0.f;
#pragma unroll
      for (int nt = 0; nt < 4; nt++) {
        const float p = __expf(s[mt][nt][r] - rm[r]);
        s[mt][nt][r] = p;
        acc += p;
      }
      sm[r] = acc;
    }
#pragma unroll
    for (int mk = 1; mk < 16; mk <<= 1)
#pragma unroll
      for (int r = 0; r < 4; r++) sm[r] += __shfl_xor(sm[r], mk);
#pragma unroll
    for (int r = 0; r < 4; r++) inv[r] = 1.0f / sm[r];
#pragma unroll
    for (int nt = 0; nt < 4; nt++)
#pragma unroll
      for (int r = 0; r < 4; r++) {
        const int R = mt * 16 + ((lane >> 4) << 2) + r;
        const int C = (lane & 15) + nt * 16;
        Pl[R * 64 + (C ^ ((R & 7) << 3))] = f2bu(s[mt][nt][r] * inv[r]);
      }
  }

  f32x4 o[4][2];
#pragma unroll
  for (int mt = 0; mt < 4; mt++)
#pragma unroll
    for (int n2 = 0; n2 < 2; n2++) o[mt][n2] = (f32x4){0.f, 0.f, 0.f, 0.f};
#pragma unroll
  for (int kk = 0; kk < 2; kk++) {
    const int kb = kk * 64 + ((lane >> 4) << 4);
    bf16x8 vb[2];
#pragma unroll
    for (int n2 = 0; n2 < 2; n2++) {
      const int d = (lane & 15) + n2 * 16;
      vb[n2] = *(const bf16x8*)((const char*)Vt + d * 128 + (kb ^ ((d & 7) << 4)));
    }
#pragma unroll
    for (int mt = 0; mt < 4; mt++) {
      const int R = (lane & 15) + mt * 16;
      const bf16x8 pa = *(const bf16x8*)((const char*)Pl + R * 128 + (kb ^ ((R & 7) << 4)));
#pragma unroll
      for (int n2 = 0; n2 < 2; n2++)
        o[mt][n2] = __builtin_amdgcn_mfma_f32_16x16x32_bf16(pa, vb[n2], o[mt][n2], 0, 0, 0);
    }
  }

#pragma unroll
  for (int mt = 0; mt < 4; mt++)
#pragma unroll
    for (int r = 0; r < 4; r++) {
      const int R = mt * 16 + ((lane >> 4) << 2) + r;
      if (R < 49) {
        bf16* orow = aout + (size_t)(wid * 49 + R) * 192 + h * 32;
#pragma unroll
        for (int n2 = 0; n2 < 2; n2++)
          orow[n2 * 16 + (lane & 15)] = __float2bfloat16(o[mt][n2][r]);
      }
    }
}

extern "C" void kernel_launch(void* const* d_in, const int* in_sizes, int n_in,
                              void* d_out, int out_size, void* d_ws, size_t ws_size,
                              hipStream_t stream)
{
  (void)in_sizes; (void)n_in; (void)out_size;
  const float* x     = (const float*)d_in[0];
  const float* ln1g  = (const float*)d_in[1];
  const float* ln1b  = (const float*)d_in[2];
  const float* qkvw  = (const float*)d_in[3];
  const float* qkvb  = (const float*)d_in[4];
  const float* projw = (const float*)d_in[5];
  const float* projb = (const float*)d_in[6];
  const float* rpb   = (const float*)d_in[7];
  const float* ln2g  = (const float*)d_in[8];
  const float* ln2b  = (const float*)d_in[9];
  const float* fc1w  = (const float*)d_in[10];
  const float* fc1b  = (const float*)d_in[11];
  const float* fc2w  = (const float*)d_in[12];
  const float* fc2b  = (const float*)d_in[13];
  float* out = (float*)d_out;
  char* ws   = (char*)d_ws;

  // ---- bf16 weight copies at head of ws (884736 B total) ----
  bf16* wqkv = (bf16*)(ws);              // 110592 el
  bf16* wproj = (bf16*)(ws + 221184);    //  36864 el
  bf16* wfc1 = (bf16*)(ws + 294912);     // 147456 el
  bf16* wfc2 = (bf16*)(ws + 589824);     // 147456 el
  cvt_kernel<<<dim3(432), dim3(256), 0, stream>>>(qkvw, wqkv, 110592);
  cvt_kernel<<<dim3(144), dim3(256), 0, stream>>>(projw, wproj, 36864);
  cvt_kernel<<<dim3(576), dim3(256), 0, stream>>>(fc1w, wfc1, 147456);
  cvt_kernel<<<dim3(576), dim3(256), 0, stream>>>(fc2w, wfc2, 147456);

  char* cws = ws + 884736;
  const size_t avail = (ws_size > 884736ull) ? ws_size - 884736ull : 0;

  // ---- attention pipeline, chunked over batch (permutes are batch-local) ----
  int Bc = 32;
  while (Bc > 2 && (size_t)Bc * 4816896ull > avail) Bc >>= 1;
  const int nb = 32 / Bc;
  bf16* qkv_c  = (bf16*)cws;
  bf16* hwin_c = (bf16*)(cws + (size_t)Bc * 3612672ull);

  for (int c = 0; c < nb; c++) {
    const int R0 = c * Bc * 3136;       // global window-row offset
    const int Mc = Bc * 3136;
    const int MT = Mc / 64;             // 64-row m-tiles
    const int Gq = (MT < 85) ? MT : 85;
    const int Gp = (MT < 256) ? MT : 256;
    ln_kernel<true><<<dim3(Mc / 4), dim3(256), 0, stream>>>(x, ln1g, ln1b, hwin_c, R0);
    pgemm_kernel<0><<<dim3(3, Gq), dim3(512), 0, stream>>>(hwin_c, wqkv, qkvb, nullptr, qkv_c, 576, 0, MT);
    attn_kernel<<<dim3(Bc * 64, 6), dim3(64), 0, stream>>>(qkv_c, rpb, hwin_c);
    pgemm_kernel<1><<<dim3(1, Gp), dim3(512), 0, stream>>>(hwin_c, wproj, projb, x, out, 192, R0, MT);
  }

  // ---- MLP (unfused), chunked over rows ----
  int Rc = 100352;
  while (Rc > 6272 && (size_t)Rc * 1920ull > avail) Rc >>= 1;
  bf16* ln2_c = (bf16*)cws;
  bf16* a1_c  = (bf16*)(cws + (size_t)Rc * 384ull);

  for (int r0 = 0; r0 < 100352; r0 += Rc) {
    const int MT1 = Rc / 64;
    const int G1  = (MT1 < 64) ? MT1 : 64;
    ln_kernel<false><<<dim3(Rc / 4), dim3(256), 0, stream>>>(out + (size_t)r0 * 192, ln2g, ln2b, ln2_c, 0);
    pgemm_kernel<2><<<dim3(4, G1), dim3(512), 0, stream>>>(ln2_c, wfc1, fc1b, nullptr, a1_c, 768, 0, MT1);
    gemm_kernel<<<dim3(1, Rc / 128), dim3(512), 0, stream>>>(a1_c, wfc2, fc2b, out + (size_t)r0 * 192, 192, 768);
  }
}